// Round 8
// baseline (230.963 us; speedup 1.0000x reference)
//
#include <hip/hip_runtime.h>

#define BB   4
#define NGT  20
#define TT   8
#define PP   25600
#define CC   40
#define TPB  512
#define SUPP 1e9f
#define INNER_TH 0.5f

// pack bits: [0]=claimed [1:6]=ml label [7:13]=mi id [14]=md valid
//            [15:20]=md class [21:25]=md raw-gt-index (for exact score recompute)
#define PK_CLAIM  1u
#define PK_LAB_SH 1
#define PK_ID_SH  7
#define PK_MDV    (1u << 14)
#define PK_MDC_SH 15
#define PK_MDN_SH 21

__device__ inline unsigned long long shfl_down_u64(unsigned long long v, int off) {
    unsigned lo = (unsigned)v, hi = (unsigned)(v >> 32);
    lo = __shfl_down(lo, off, 64);
    hi = __shfl_down(hi, off, 64);
    return ((unsigned long long)hi << 32) | (unsigned long long)lo;
}

// geometry for (b, raw n, t) — identical IEEE ops in match and paint
__device__ inline float4 make_geo(const float* __restrict__ gt_boxes, int b, int n, int t) {
    const float* bx = gt_boxes + ((size_t)(b * NGT + n) * TT + t) * 4;
    float x1 = bx[0], y1 = bx[1], x2 = bx[2], y2 = bx[3];
    float4 g;
    g.x = __fmul_rn(__fadd_rn(x1, x2), 0.5f);
    g.y = __fmul_rn(__fadd_rn(y1, y2), 0.5f);
    g.z = fmaxf(__fsub_rn(x2, x1), 0.05f);
    g.w = fmaxf(__fsub_rn(y2, y1), 0.05f);
    return g;
}

// exact distance for grid point (px,py) vs gt geometry g — identical IEEE ops to ref
__device__ inline float point_dist(int px, int py, float4 g) {
    float rxv = __fdiv_rn((float)px + 0.5f, 160.0f);  // == ref_points formula exactly
    float ryv = __fdiv_rn((float)py + 0.5f, 160.0f);
    float dx = __fdiv_rn(__fsub_rn(g.x, rxv), g.z);
    float dy = __fdiv_rn(__fsub_rn(g.y, ryv), g.w);
    return __fadd_rn(__fmul_rn(dx, dx), __fmul_rn(dy, dy));  // no FMA contraction
}

// ---------------- match: one block per (b,t); pure-LDS loop; one coalesced dump ----
__global__ __launch_bounds__(TPB) void match_kernel(
        const int*   __restrict__ gt_labels,
        const float* __restrict__ gt_boxes,
        const int*   __restrict__ gt_ids,
        unsigned* __restrict__ packs_g) {  // [B*T][P]
    int bt = blockIdx.x;            // b*T + t
    int b  = bt >> 3;
    int t  = bt & 7;
    int tid = threadIdx.x;

    __shared__ unsigned s_pack[PP];           // 102400 B
    __shared__ float  s_area[NGT];
    __shared__ int    s_valid[NGT];
    __shared__ int    s_order[NGT];
    __shared__ int    s_any[NGT];             // one flag per active slot: never reused
    __shared__ float4 s_geo[NGT];
    __shared__ int4   s_meta[NGT];            // {label, id, active, raw n} (sorted order)
    __shared__ int    s_actlist[NGT];
    __shared__ int    s_actcnt;
    __shared__ unsigned long long s_wave[TPB / 64];
    __shared__ unsigned long long s_bcast;

    // ---- phase 0: zero pack state, per-gt mean area / validity ----
    {
        uint4 z = make_uint4(0u, 0u, 0u, 0u);
        for (int i = tid; i < PP / 4; i += TPB) ((uint4*)s_pack)[i] = z;
    }
    if (tid < NGT) {
        const float* bx = gt_boxes + (size_t)(b * NGT + tid) * TT * 4;
        float a[TT];
        int anyPos = 0;
        for (int f = 0; f < TT; f++) {
            float w = __fsub_rn(bx[f * 4 + 2], bx[f * 4 + 0]);
            float h = __fsub_rn(bx[f * 4 + 3], bx[f * 4 + 1]);
            a[f] = __fmul_rn(w, h);
            anyPos |= (w > 0.0f && h > 0.0f) ? 1 : 0;
        }
        // numpy pairwise sum order for n=8, then * 1/8
        float s = __fadd_rn(__fadd_rn(__fadd_rn(a[0], a[1]), __fadd_rn(a[2], a[3])),
                            __fadd_rn(__fadd_rn(a[4], a[5]), __fadd_rn(a[6], a[7])));
        s_area[tid]  = __fmul_rn(s, 0.125f);
        s_valid[tid] = (anyPos && gt_labels[b * NGT + tid] >= 0) ? 1 : 0;
        s_any[tid]   = 0;
    }
    __syncthreads();

    // ---- phase 1: stable ascending argsort by rank counting ----
    if (tid < NGT) {
        float an = s_area[tid];
        int r = 0;
        for (int m2 = 0; m2 < NGT; m2++) {
            float am = s_area[m2];
            r += (am < an || (am == an && m2 < tid)) ? 1 : 0;
        }
        s_order[r] = tid;
    }
    __syncthreads();

    // ---- phase 2: per sorted slot, this frame's geometry/meta; compact active list ----
    if (tid < NGT) {
        int n   = s_order[tid];
        int src = b * NGT + n;
        s_geo[tid] = make_geo(gt_boxes, b, n, t);
        int id = gt_ids[src * TT + t];
        int4 mm;
        mm.x = gt_labels[src];
        mm.y = id;
        mm.z = (s_valid[n] && id != -1) ? 1 : 0;
        mm.w = n;                              // raw index for paint's score recompute
        s_meta[tid] = mm;
    }
    __syncthreads();
    if (tid == 0) {
        int c = 0;
        for (int k = 0; k < NGT; k++)
            if (s_meta[k].z) s_actlist[c++] = k;  // preserves sorted order
        s_actcnt = c;
    }
    // visibility of s_actlist/s_actcnt: covered by loop-top barrier A (j=0)

    __syncthreads();
    int actcnt = s_actcnt;

    for (int j = 0; j < actcnt; j++) {
        // barrier A semantics: prior iteration's claims visible (see end of loop)
        int slot = s_actlist[j];
        int4 m  = s_meta[slot];
        float4 g = s_geo[slot];

        // conservative rect: superset of {d < 0.5} (|dx_n| < sqrt(0.5) per axis), +slop
        float ex = __fmul_rn(g.z, 0.70711f);
        float ey = __fmul_rn(g.w, 0.70711f);
        int x0 = max(0,   (int)floorf((g.x - ex) * 160.0f - 0.5f) - 1);
        int x1 = min(159, (int)ceilf ((g.x + ex) * 160.0f - 0.5f) + 1);
        int y0 = max(0,   (int)floorf((g.y - ey) * 160.0f - 0.5f) - 1);
        int y1 = min(159, (int)ceilf ((g.y + ey) * 160.0f - 0.5f) + 1);
        int rw = x1 - x0 + 1;
        int M  = rw * (y1 - y0 + 1);

        // single scan with inline claiming: if inner.any() the ref claims exactly the
        // unclaimed inner points — each is owned by one thread, so claim immediately.
        // If no thread claims, state is unchanged and the fallback below is exact.
        unsigned base = PK_CLAIM | ((unsigned)m.x << PK_LAB_SH) |
                        ((unsigned)m.y << PK_ID_SH) | PK_MDV |
                        ((unsigned)m.x << PK_MDC_SH) |
                        ((unsigned)m.w << PK_MDN_SH);
        int found = 0;
        for (int i = tid; i < M; i += TPB) {
            int r  = i / rw;
            int px = x0 + (i - r * rw);
            int py = y0 + r;
            int p  = py * 160 + px;
            if (!(s_pack[p] & PK_CLAIM)) {
                float d = point_dist(px, py, g);
                if (d < INNER_TH) {            // score recomputed in paint from (n,p)
                    s_pack[p] = base;
                    found = 1;
                }
            }
        }
        if (found) s_any[j] = 1;
        __syncthreads();                       // B: consensus + claims visible

        if (!s_any[j]) {
            // fallback: single argmin over suppressed full frame (exact ref semantics:
            // claimed points hold 1e9; ties -> first index). No claims happened above.
            unsigned long long key = ~0ULL;
            for (int p = tid; p < PP; p += TPB) {
                float deff;
                if (s_pack[p] & PK_CLAIM) {
                    deff = SUPP;
                } else {
                    int py = p / 160;
                    int px = p - py * 160;
                    deff = point_dist(px, py, g);
                }
                unsigned long long kk =
                    ((unsigned long long)__float_as_uint(deff) << 32) |
                    (unsigned long long)(unsigned)p;
                key = (kk < key) ? kk : key;
            }
            unsigned long long v = key;
            for (int off = 32; off > 0; off >>= 1) {
                unsigned long long o = shfl_down_u64(v, off);
                v = (o < v) ? o : v;
            }
            int lane = tid & 63, wave = tid >> 6;
            if (lane == 0) s_wave[wave] = v;
            __syncthreads();
            if (tid == 0) {
                unsigned long long mval = s_wave[0];
                for (int w = 1; w < TPB / 64; w++) mval = (s_wave[w] < mval) ? s_wave[w] : mval;
                s_bcast = mval;
            }
            __syncthreads();
            unsigned long long gmin = s_bcast;
            float minv = __uint_as_float((unsigned)(gmin >> 32));
            int minp = (int)(unsigned)(gmin & 0xffffffffu);
            if ((minp & (TPB - 1)) == tid) {   // unique owner thread
                unsigned npk = PK_CLAIM | ((unsigned)m.x << PK_LAB_SH) |
                               ((unsigned)m.y << PK_ID_SH);
                if (minv < SUPP) {
                    // winner was unclaimed: d >= 0.5 everywhere unclaimed => ref md
                    // write = 0 on an all-zero row: no md record.
                    s_pack[minp] = npk;
                } else {
                    // all points claimed (argmin of all-1e9 = index 0). ref writes
                    // md[minp][lab] = 0: erase prior record iff same class.
                    unsigned old = s_pack[minp];
                    unsigned mdbits = old & (PK_MDV | (63u << PK_MDC_SH) | (31u << PK_MDN_SH));
                    if ((old & PK_MDV) &&
                        ((old >> PK_MDC_SH) & 63u) == (unsigned)m.x) mdbits = 0u;
                    s_pack[minp] = npk | mdbits;
                }
            }
            __syncthreads();                   // fallback claim visible before next gt
        }
        // common path: barrier B already made this gt's claims visible
    }

    // ---- dump pack state (coalesced, only global traffic of this kernel) ----
    __syncthreads();
    uint4* dst = (uint4*)(packs_g + (size_t)bt * PP);
    for (int i = tid; i < PP / 4; i += TPB) dst[i] = ((const uint4*)s_pack)[i];
}

// ---------------- paint: md via LDS-staged 256-point tiles; ml/mi via uint4 packs ----
// blocks [0, MD_BLOCKS): md tiles. blocks [MD_BLOCKS, MD_BLOCKS+MLMI_BLOCKS): ml+mi.
#define MD_BLOCKS   3200   // 819200 points / 256 per tile
#define MLMI_BLOCKS 400    // 409600 float4s / (256 threads * 4 rounds)
__global__ __launch_bounds__(256) void paint_kernel(
        const unsigned* __restrict__ packs,
        const float*    __restrict__ gt_boxes,
        float4* __restrict__ out4) {
    const int ML4 = BB * TT * PP / 4;             // 204800 float4s
    const int MD4 = BB * TT * PP * CC / 4;        // 8192000 float4s
    int bi  = blockIdx.x;
    int tid = threadIdx.x;

    if (bi < MD_BLOCKS) {
        // ---- md tile: 256 points -> 2560 contiguous float4s ----
        __shared__ int   s_cls[256];
        __shared__ float s_sc[256];
        int pt = bi * 256 + tid;                  // global point index
        unsigned pk = packs[pt];
        int   cls = -1;
        float sc  = 0.0f;
        if (pk & PK_MDV) {
            cls = (int)((pk >> PK_MDC_SH) & 63u);
            int n  = (int)((pk >> PK_MDN_SH) & 31u);
            int bt = pt / PP;
            int p  = pt - bt * PP;
            float4 g = make_geo(gt_boxes, bt >> 3, n, bt & 7);
            float d  = point_dist(p - (p / 160) * 160, p / 160, g);
            sc = __fsub_rn(1.0f, __fmul_rn(2.0f, d));   // exact: same ops as ref
        }
        s_cls[tid] = cls;
        s_sc[tid]  = sc;
        __syncthreads();
        float4* dst = out4 + ML4 + (size_t)bi * 2560;
#pragma unroll
        for (int r = 0; r < 10; r++) {
            int f   = r * 256 + tid;              // float4 within tile
            int ptl = f / 10;                     // local point
            int c0  = (f - ptl * 10) << 2;        // first class of this float4
            int c   = s_cls[ptl];
            float4 v = make_float4(0.0f, 0.0f, 0.0f, 0.0f);
            if (c >= c0 && c < c0 + 4) ((float*)&v)[c - c0] = s_sc[ptl];
            dst[f] = v;
        }
    } else {
        // ---- ml + mi: each thread 4 float4s, 16B pack load per float4 ----
        int base = (bi - MD_BLOCKS) * 1024;       // float4 index in [0, 409600)
#pragma unroll
        for (int r = 0; r < 4; r++) {
            int f = base + r * 256 + tid;
            int isMi = (f >= ML4);
            int pf = isMi ? (f - ML4) : f;        // pack float4 index
            uint4 pk4 = ((const uint4*)packs)[pf];
            float4 v;
            int sh = isMi ? PK_ID_SH : PK_LAB_SH;
            unsigned msk = isMi ? 127u : 63u;
            v.x = (pk4.x & PK_CLAIM) ? (float)((pk4.x >> sh) & msk) : -1.0f;
            v.y = (pk4.y & PK_CLAIM) ? (float)((pk4.y >> sh) & msk) : -1.0f;
            v.z = (pk4.z & PK_CLAIM) ? (float)((pk4.z >> sh) & msk) : -1.0f;
            v.w = (pk4.w & PK_CLAIM) ? (float)((pk4.w >> sh) & msk) : -1.0f;
            out4[isMi ? (ML4 + MD4 + pf) : f] = v;
        }
    }
}

extern "C" void kernel_launch(void* const* d_in, const int* in_sizes, int n_in,
                              void* d_out, int out_size, void* d_ws, size_t ws_size,
                              hipStream_t stream) {
    const int*   gt_labels = (const int*)d_in[0];
    const float* gt_boxes  = (const float*)d_in[1];
    const int*   gt_ids    = (const int*)d_in[2];
    // d_in[3] = ref_points (regular 160x160 grid — computed exactly in-kernel)
    // d_in[4] = spatial_shapes (unused; H=W=160 fixed)

    unsigned* packs = (unsigned*)d_ws;            // 3.2 MB

    match_kernel<<<BB * TT, TPB, 0, stream>>>(gt_labels, gt_boxes, gt_ids, packs);
    paint_kernel<<<MD_BLOCKS + MLMI_BLOCKS, 256, 0, stream>>>(packs, gt_boxes,
                                                              (float4*)d_out);
}

// Round 9
// 217.393 us; speedup vs baseline: 1.0624x; 1.0624x over previous
//
#include <hip/hip_runtime.h>

#define BB   4
#define NGT  20
#define TT   8
#define PP   25600
#define CC   40
#define TPB  1024
#define SUPP 1e9f
#define INNER_TH 0.5f

// pack bits: [0]=claimed [1:6]=ml label [7:13]=mi id [14]=md valid
//            [15:20]=md class [21:25]=md raw-gt-index (for exact score recompute)
#define PK_CLAIM  1u
#define PK_LAB_SH 1
#define PK_ID_SH  7
#define PK_MDV    (1u << 14)
#define PK_MDC_SH 15
#define PK_MDN_SH 21

__device__ inline unsigned long long shfl_down_u64(unsigned long long v, int off) {
    unsigned lo = (unsigned)v, hi = (unsigned)(v >> 32);
    lo = __shfl_down(lo, off, 64);
    hi = __shfl_down(hi, off, 64);
    return ((unsigned long long)hi << 32) | (unsigned long long)lo;
}

// geometry for (b, raw n, t) — identical IEEE ops in match and paint
__device__ inline float4 make_geo(const float* __restrict__ gt_boxes, int b, int n, int t) {
    const float* bx = gt_boxes + ((size_t)(b * NGT + n) * TT + t) * 4;
    float x1 = bx[0], y1 = bx[1], x2 = bx[2], y2 = bx[3];
    float4 g;
    g.x = __fmul_rn(__fadd_rn(x1, x2), 0.5f);
    g.y = __fmul_rn(__fadd_rn(y1, y2), 0.5f);
    g.z = fmaxf(__fsub_rn(x2, x1), 0.05f);
    g.w = fmaxf(__fsub_rn(y2, y1), 0.05f);
    return g;
}

// exact distance for grid point (px,py) vs gt geometry g — identical IEEE ops to ref
__device__ inline float point_dist(int px, int py, float4 g) {
    float rxv = __fdiv_rn((float)px + 0.5f, 160.0f);  // == ref_points formula exactly
    float ryv = __fdiv_rn((float)py + 0.5f, 160.0f);
    float dx = __fdiv_rn(__fsub_rn(g.x, rxv), g.z);
    float dy = __fdiv_rn(__fsub_rn(g.y, ryv), g.w);
    return __fadd_rn(__fmul_rn(dx, dx), __fmul_rn(dy, dy));  // no FMA contraction
}

// ---------------- match: one block per (b,t); pure-LDS loop; one coalesced dump ----
__global__ __launch_bounds__(TPB) void match_kernel(
        const int*   __restrict__ gt_labels,
        const float* __restrict__ gt_boxes,
        const int*   __restrict__ gt_ids,
        unsigned* __restrict__ packs_g) {  // [B*T][P]
    int bt = blockIdx.x;            // b*T + t
    int b  = bt >> 3;
    int t  = bt & 7;
    int tid = threadIdx.x;

    __shared__ unsigned s_pack[PP];           // 102400 B
    __shared__ float  s_area[NGT];
    __shared__ int    s_valid[NGT];
    __shared__ int    s_order[NGT];
    __shared__ int    s_any[NGT];             // one flag per active slot: never reused
    __shared__ float4 s_geo[NGT];
    __shared__ int4   s_meta[NGT];            // {label, id, active, raw n} (sorted order)
    __shared__ int    s_actlist[NGT];
    __shared__ int    s_actcnt;
    __shared__ unsigned long long s_wave[TPB / 64];
    __shared__ unsigned long long s_bcast;

    // ---- phase 0: zero pack state, per-gt mean area / validity ----
    {
        uint4 z = make_uint4(0u, 0u, 0u, 0u);
        for (int i = tid; i < PP / 4; i += TPB) ((uint4*)s_pack)[i] = z;
    }
    if (tid < NGT) {
        const float* bx = gt_boxes + (size_t)(b * NGT + tid) * TT * 4;
        float a[TT];
        int anyPos = 0;
        for (int f = 0; f < TT; f++) {
            float w = __fsub_rn(bx[f * 4 + 2], bx[f * 4 + 0]);
            float h = __fsub_rn(bx[f * 4 + 3], bx[f * 4 + 1]);
            a[f] = __fmul_rn(w, h);
            anyPos |= (w > 0.0f && h > 0.0f) ? 1 : 0;
        }
        // numpy pairwise sum order for n=8, then * 1/8
        float s = __fadd_rn(__fadd_rn(__fadd_rn(a[0], a[1]), __fadd_rn(a[2], a[3])),
                            __fadd_rn(__fadd_rn(a[4], a[5]), __fadd_rn(a[6], a[7])));
        s_area[tid]  = __fmul_rn(s, 0.125f);
        s_valid[tid] = (anyPos && gt_labels[b * NGT + tid] >= 0) ? 1 : 0;
        s_any[tid]   = 0;
    }
    __syncthreads();

    // ---- phase 1: stable ascending argsort by rank counting ----
    if (tid < NGT) {
        float an = s_area[tid];
        int r = 0;
        for (int m2 = 0; m2 < NGT; m2++) {
            float am = s_area[m2];
            r += (am < an || (am == an && m2 < tid)) ? 1 : 0;
        }
        s_order[r] = tid;
    }
    __syncthreads();

    // ---- phase 2: per sorted slot, this frame's geometry/meta; compact active list ----
    if (tid < NGT) {
        int n   = s_order[tid];
        int src = b * NGT + n;
        s_geo[tid] = make_geo(gt_boxes, b, n, t);
        int id = gt_ids[src * TT + t];
        int4 mm;
        mm.x = gt_labels[src];
        mm.y = id;
        mm.z = (s_valid[n] && id != -1) ? 1 : 0;
        mm.w = n;                              // raw index for paint's score recompute
        s_meta[tid] = mm;
    }
    __syncthreads();
    if (tid == 0) {
        int c = 0;
        for (int k = 0; k < NGT; k++)
            if (s_meta[k].z) s_actlist[c++] = k;  // preserves sorted order
        s_actcnt = c;
    }
    __syncthreads();
    int actcnt = s_actcnt;

    for (int j = 0; j < actcnt; j++) {
        // invariant at loop top: all prior claims visible (barrier B / fallback barrier)
        int slot = s_actlist[j];
        int4 m  = s_meta[slot];
        float4 g = s_geo[slot];

        // conservative rect: superset of {d < 0.5} (|dx_n| < sqrt(0.5) per axis), +slop
        float ex = __fmul_rn(g.z, 0.70711f);
        float ey = __fmul_rn(g.w, 0.70711f);
        int x0 = max(0,   (int)floorf((g.x - ex) * 160.0f - 0.5f) - 1);
        int x1 = min(159, (int)ceilf ((g.x + ex) * 160.0f - 0.5f) + 1);
        int y0 = max(0,   (int)floorf((g.y - ey) * 160.0f - 0.5f) - 1);
        int y1 = min(159, (int)ceilf ((g.y + ey) * 160.0f - 0.5f) + 1);
        int rw = x1 - x0 + 1;
        int M  = rw * (y1 - y0 + 1);

        // single scan with inline claiming: if inner.any() the ref claims exactly the
        // unclaimed inner points — each point is visited by exactly one thread, so a
        // claim can't change any other decision for this gt. If no thread claims,
        // state is unchanged and the fallback below is exact.
        unsigned base = PK_CLAIM | ((unsigned)m.x << PK_LAB_SH) |
                        ((unsigned)m.y << PK_ID_SH) | PK_MDV |
                        ((unsigned)m.x << PK_MDC_SH) |
                        ((unsigned)m.w << PK_MDN_SH);
        int found = 0;
        {
            // division-free strided (r,c) walk: one div per gt, then stepping
            int r  = tid / rw;                 // only vector div in the loop body
            int c  = tid - r * rw;
            int dr = TPB / rw;                 // uniform per gt
            int dc = TPB - dr * rw;            // TPB % rw
            for (int i = tid; i < M; i += TPB) {
                int px = x0 + c;
                int py = y0 + r;
                int p  = py * 160 + px;
                if (!(s_pack[p] & PK_CLAIM)) {
                    float d = point_dist(px, py, g);
                    if (d < INNER_TH) {        // score recomputed in paint from (n,p)
                        s_pack[p] = base;
                        found = 1;
                    }
                }
                c += dc; r += dr;
                if (c >= rw) { c -= rw; r++; }
            }
        }
        if (found) s_any[j] = 1;
        __syncthreads();                       // B: consensus + claims visible

        if (!s_any[j]) {
            // fallback: single argmin over suppressed full frame (exact ref semantics:
            // claimed points hold 1e9; ties -> first index). No claims happened above.
            unsigned long long key = ~0ULL;
            {
                int py = tid >> 7;             // tid/160 stepping base: tid in [0,1024)
                py = tid / 160;                // one div
                int px = tid - py * 160;
                for (int p = tid; p < PP; p += TPB) {
                    float deff;
                    if (s_pack[p] & PK_CLAIM) {
                        deff = SUPP;
                    } else {
                        deff = point_dist(px, py, g);
                    }
                    unsigned long long kk =
                        ((unsigned long long)__float_as_uint(deff) << 32) |
                        (unsigned long long)(unsigned)p;
                    key = (kk < key) ? kk : key;
                    px += 64; py += 6;         // 1024 = 6*160 + 64
                    if (px >= 160) { px -= 160; py++; }
                }
            }
            unsigned long long v = key;
            for (int off = 32; off > 0; off >>= 1) {
                unsigned long long o = shfl_down_u64(v, off);
                v = (o < v) ? o : v;
            }
            int lane = tid & 63, wave = tid >> 6;
            if (lane == 0) s_wave[wave] = v;
            __syncthreads();
            if (tid == 0) {
                unsigned long long mval = s_wave[0];
                for (int w = 1; w < TPB / 64; w++) mval = (s_wave[w] < mval) ? s_wave[w] : mval;
                s_bcast = mval;
            }
            __syncthreads();
            unsigned long long gmin = s_bcast;
            float minv = __uint_as_float((unsigned)(gmin >> 32));
            int minp = (int)(unsigned)(gmin & 0xffffffffu);
            if ((minp & (TPB - 1)) == tid) {   // unique owner thread
                unsigned npk = PK_CLAIM | ((unsigned)m.x << PK_LAB_SH) |
                               ((unsigned)m.y << PK_ID_SH);
                if (minv < SUPP) {
                    // winner was unclaimed: d >= 0.5 everywhere unclaimed => ref md
                    // write = 0 on an all-zero row: no md record.
                    s_pack[minp] = npk;
                } else {
                    // all points claimed (argmin of all-1e9 = index 0). ref writes
                    // md[minp][lab] = 0: erase prior record iff same class.
                    unsigned old = s_pack[minp];
                    unsigned mdbits = old & (PK_MDV | (63u << PK_MDC_SH) | (31u << PK_MDN_SH));
                    if ((old & PK_MDV) &&
                        ((old >> PK_MDC_SH) & 63u) == (unsigned)m.x) mdbits = 0u;
                    s_pack[minp] = npk | mdbits;
                }
            }
            __syncthreads();                   // fallback claim visible before next gt
        }
        // common path: barrier B already made this gt's claims visible
    }

    // ---- dump pack state (coalesced, only global traffic of this kernel) ----
    __syncthreads();
    uint4* dst = (uint4*)(packs_g + (size_t)bt * PP);
    for (int i = tid; i < PP / 4; i += TPB) dst[i] = ((const uint4*)s_pack)[i];
}

// ---------------- paint: md via LDS-staged 256-point tiles; ml/mi via uint4 packs ----
// blocks [0, MD_BLOCKS): md tiles. blocks [MD_BLOCKS, MD_BLOCKS+MLMI_BLOCKS): ml+mi.
#define MD_BLOCKS   3200   // 819200 points / 256 per tile
#define MLMI_BLOCKS 400    // 409600 float4s / (256 threads * 4 rounds)
__global__ __launch_bounds__(256) void paint_kernel(
        const unsigned* __restrict__ packs,
        const float*    __restrict__ gt_boxes,
        float4* __restrict__ out4) {
    const int ML4 = BB * TT * PP / 4;             // 204800 float4s
    const int MD4 = BB * TT * PP * CC / 4;        // 8192000 float4s
    int bi  = blockIdx.x;
    int tid = threadIdx.x;

    if (bi < MD_BLOCKS) {
        // ---- md tile: 256 points -> 2560 contiguous float4s ----
        __shared__ int   s_cls[256];
        __shared__ float s_sc[256];
        int pt = bi * 256 + tid;                  // global point index
        unsigned pk = packs[pt];
        int   cls = -1;
        float sc  = 0.0f;
        if (pk & PK_MDV) {
            cls = (int)((pk >> PK_MDC_SH) & 63u);
            int n  = (int)((pk >> PK_MDN_SH) & 31u);
            int bt = pt / PP;
            int p  = pt - bt * PP;
            float4 g = make_geo(gt_boxes, bt >> 3, n, bt & 7);
            float d  = point_dist(p - (p / 160) * 160, p / 160, g);
            sc = __fsub_rn(1.0f, __fmul_rn(2.0f, d));   // exact: same ops as ref
        }
        s_cls[tid] = cls;
        s_sc[tid]  = sc;
        __syncthreads();
        float4* dst = out4 + ML4 + (size_t)bi * 2560;
#pragma unroll
        for (int r = 0; r < 10; r++) {
            int f   = r * 256 + tid;              // float4 within tile
            int ptl = f / 10;                     // local point
            int c0  = (f - ptl * 10) << 2;        // first class of this float4
            int c   = s_cls[ptl];
            float4 v = make_float4(0.0f, 0.0f, 0.0f, 0.0f);
            if (c >= c0 && c < c0 + 4) ((float*)&v)[c - c0] = s_sc[ptl];
            dst[f] = v;
        }
    } else {
        // ---- ml + mi: each thread 4 float4s, 16B pack load per float4 ----
        int base = (bi - MD_BLOCKS) * 1024;       // float4 index in [0, 409600)
#pragma unroll
        for (int r = 0; r < 4; r++) {
            int f = base + r * 256 + tid;
            int isMi = (f >= ML4);
            int pf = isMi ? (f - ML4) : f;        // pack float4 index
            uint4 pk4 = ((const uint4*)packs)[pf];
            float4 v;
            int sh = isMi ? PK_ID_SH : PK_LAB_SH;
            unsigned msk = isMi ? 127u : 63u;
            v.x = (pk4.x & PK_CLAIM) ? (float)((pk4.x >> sh) & msk) : -1.0f;
            v.y = (pk4.y & PK_CLAIM) ? (float)((pk4.y >> sh) & msk) : -1.0f;
            v.z = (pk4.z & PK_CLAIM) ? (float)((pk4.z >> sh) & msk) : -1.0f;
            v.w = (pk4.w & PK_CLAIM) ? (float)((pk4.w >> sh) & msk) : -1.0f;
            out4[isMi ? (ML4 + MD4 + pf) : f] = v;
        }
    }
}

extern "C" void kernel_launch(void* const* d_in, const int* in_sizes, int n_in,
                              void* d_out, int out_size, void* d_ws, size_t ws_size,
                              hipStream_t stream) {
    const int*   gt_labels = (const int*)d_in[0];
    const float* gt_boxes  = (const float*)d_in[1];
    const int*   gt_ids    = (const int*)d_in[2];
    // d_in[3] = ref_points (regular 160x160 grid — computed exactly in-kernel)
    // d_in[4] = spatial_shapes (unused; H=W=160 fixed)

    unsigned* packs = (unsigned*)d_ws;            // 3.2 MB

    match_kernel<<<BB * TT, TPB, 0, stream>>>(gt_labels, gt_boxes, gt_ids, packs);
    paint_kernel<<<MD_BLOCKS + MLMI_BLOCKS, 256, 0, stream>>>(packs, gt_boxes,
                                                              (float4*)d_out);
}